// Round 2
// baseline (676.398 us; speedup 1.0000x reference)
//
#include <hip/hip_runtime.h>
#include <hip/hip_bf16.h>

// BranchingQNetwork fused forward for MI355X (gfx950).
// B=32, N=2048, OBS=256, HID=128, n1=n2=8.

typedef __attribute__((ext_vector_type(4))) float f32x4;
typedef __attribute__((ext_vector_type(8))) short bf16x8;
typedef __attribute__((ext_vector_type(4))) unsigned int u32x4;

#define LOG2E 1.44269504088896340736f
#define NEGC 9.0e15f

static __device__ __forceinline__ unsigned short f2bf(float f) {
  unsigned int x = __builtin_bit_cast(unsigned int, f);
  unsigned int r = (x + 0x7fffu + ((x >> 16) & 1u)) >> 16;   // RNE
  return (unsigned short)r;
}
static __device__ __forceinline__ float bf2f(unsigned short u) {
  return __builtin_bit_cast(float, ((unsigned int)u) << 16);
}
static __device__ __forceinline__ unsigned int pack2bf(float lo, float hi) {
  return (unsigned int)f2bf(lo) | ((unsigned int)f2bf(hi) << 16);
}
static __device__ __forceinline__ f32x4 mfma16(bf16x8 a, bf16x8 b, f32x4 c) {
  return __builtin_amdgcn_mfma_f32_16x16x32_bf16(a, b, c, 0, 0, 0);
}

// ---------------------------------------------------------------------------
// Kernel 0: weight prep. WT (384 cols = [q|k|v]) transposed to [col][256] bf16
// hi/lo split; WoutT transposed to [col][128] bf16.
// ---------------------------------------------------------------------------
__global__ void prep_kernel(const float* __restrict__ Wv, const float* __restrict__ Wk,
                            const float* __restrict__ Wq, const float* __restrict__ Wout,
                            unsigned short* __restrict__ WT_hi, unsigned short* __restrict__ WT_lo,
                            unsigned short* __restrict__ WoutT) {
  int idx = blockIdx.x * 256 + threadIdx.x;
  if (idx < 384 * 256) {
    int j = idx >> 8;      // output col 0..383  (0..127=q, 128..255=k, 256..383=v)
    int c = idx & 255;     // k index
    const float* W = (j < 128) ? Wq : (j < 256) ? Wk : Wv;
    float w = W[c * 128 + (j & 127)];
    unsigned short hi = f2bf(w);
    WT_hi[idx] = hi;
    WT_lo[idx] = f2bf(w - bf2f(hi));
  } else {
    int i2 = idx - 384 * 256;
    if (i2 < 128 * 128) {
      int j = i2 >> 7, c = i2 & 127;
      WoutT[i2] = f2bf(Wout[c * 128 + j]);
    }
  }
}

// ---------------------------------------------------------------------------
// Kernel 1: fused QKV projection. 64 rows/block, 4 waves x 16 rows x 384 cols.
// 3-pass hi/lo split MFMA, relu+bias; q -> bf16, k -> hi/lo bf16,
// v -> staged in LDS and written TRANSPOSED as vT[b][h][n].
// ---------------------------------------------------------------------------
__global__ __launch_bounds__(256) void proj_kernel(
    const float* __restrict__ x,
    const unsigned short* __restrict__ WT_hi, const unsigned short* __restrict__ WT_lo,
    const float* __restrict__ bq, const float* __restrict__ bk, const float* __restrict__ bv,
    unsigned short* __restrict__ q_bf, unsigned short* __restrict__ k_hi,
    unsigned short* __restrict__ k_lo, unsigned short* __restrict__ vT) {
  __shared__ unsigned short vbuf[64][132];
  const int lane = threadIdx.x & 63, wid = threadIdx.x >> 6;
  const int qq = lane >> 4, hh = lane & 15;
  const long rowA = (long)blockIdx.x * 64 + wid * 16 + hh;  // A-frag row
  const f32x4 zero4 = {0.f, 0.f, 0.f, 0.f};
  f32x4 acc[24];
#pragma unroll
  for (int t = 0; t < 24; ++t) acc[t] = zero4;

  for (int kc = 0; kc < 8; ++kc) {
    const float* xp = x + rowA * 256 + kc * 32 + qq * 8;
    f32x4 x0 = *(const f32x4*)xp;
    f32x4 x1 = *(const f32x4*)(xp + 4);
    bf16x8 ah, al;
#pragma unroll
    for (int j = 0; j < 8; ++j) {
      float f = (j < 4) ? x0[j] : x1[j - 4];
      unsigned short h = f2bf(f);
      ah[j] = (short)h;
      al[j] = (short)f2bf(f - bf2f(h));
    }
#pragma unroll
    for (int t = 0; t < 24; ++t) {
      const unsigned short* wp = WT_hi + (t * 16 + hh) * 256 + kc * 32 + qq * 8;
      const unsigned short* wl = WT_lo + (t * 16 + hh) * 256 + kc * 32 + qq * 8;
      bf16x8 bh = *(const bf16x8*)wp;
      bf16x8 bl = *(const bf16x8*)wl;
      acc[t] = mfma16(ah, bh, acc[t]);
      acc[t] = mfma16(al, bh, acc[t]);
      acc[t] = mfma16(ah, bl, acc[t]);
    }
  }
  const long rowC = (long)blockIdx.x * 64 + wid * 16 + qq * 4;
  const int rowL = wid * 16 + qq * 4;
#pragma unroll
  for (int t = 0; t < 24; ++t) {
    const int col = t * 16 + hh;
    const int sec = t >> 3;        // 0=q 1=k 2=v (uniform per t)
    const int j = col & 127;
    const float bias = (sec == 0) ? bq[j] : (sec == 1) ? bk[j] : bv[j];
#pragma unroll
    for (int r = 0; r < 4; ++r) {
      float val = fmaxf(acc[t][r] + bias, 0.f);
      long o = (rowC + r) * 128 + j;
      if (sec == 0) {
        q_bf[o] = f2bf(val);
      } else if (sec == 1) {
        unsigned short h = f2bf(val);
        k_hi[o] = h;
        k_lo[o] = f2bf(val - bf2f(h));
      } else {
        vbuf[rowL + r][j] = f2bf(val);
      }
    }
  }
  __syncthreads();
  // cooperative transposed write: vT[(b*128 + h)*2048 + n]
  {
    const int tid = threadIdx.x;
    const int j = tid >> 1;          // h col 0..127
    const int half = tid & 1;        // n half (32 each)
    const long nbase = (long)blockIdx.x * 64;
    const int bb = (int)(nbase >> 11);
    const int noff = (int)(nbase & 2047);
    unsigned short* op = vT + ((long)bb * 128 + j) * 2048 + noff + half * 32;
#pragma unroll
    for (int g = 0; g < 4; ++g) {
      u32x4 w;
#pragma unroll
      for (int d = 0; d < 4; ++d) {
        int i = g * 8 + d * 2;
        w[d] = (unsigned int)vbuf[half * 32 + i][j] |
               ((unsigned int)vbuf[half * 32 + i + 1][j] << 16);
      }
      *(u32x4*)(op + g * 8) = w;
    }
  }
}

// ---------------------------------------------------------------------------
// Kernel 2: flash attention, ZERO LDS staging (K/V are L2-resident per batch).
// Swapped QK^T: S^T = K·Q^T via mfma(A=K_frag, B=Q_frag) -> C row=kv, col=q.
// Mask loads become dwordx4 (kv is the reg dim). Softmax scalars per lane.
// PV: O^T = V^T·P, V^T frags contiguous from pre-transposed vT.
// P C-layout -> B-frag redistribution via in-register shfl (ds_bpermute).
// Grid: 512 blocks (b = idx>>4, 128 rows per block), 4 waves x 32 rows.
// ---------------------------------------------------------------------------
__global__ __launch_bounds__(256, 2) void attn_kernel(
    const unsigned short* __restrict__ q_bf, const unsigned short* __restrict__ k_hi,
    const unsigned short* __restrict__ k_lo, const unsigned short* __restrict__ vT,
    const float* __restrict__ mask, unsigned short* __restrict__ out_att) {
  const int lane = threadIdx.x & 63, wid = threadIdx.x >> 6;
  const int qq = lane >> 4, hh = lane & 15;
  const int b = blockIdx.x >> 4;
  const int nb = blockIdx.x & 15;
  const long qbase = (long)b * 2048 + nb * 128 + wid * 32;
  const f32x4 zero4 = {0.f, 0.f, 0.f, 0.f};

  // hoisted Q fragments (B-operand): Q[q = ctq*16+hh][h = kc*32+qq*8+j]
  bf16x8 qh[2][4];
#pragma unroll
  for (int ctq = 0; ctq < 2; ++ctq)
#pragma unroll
    for (int kc = 0; kc < 4; ++kc)
      qh[ctq][kc] = *(const bf16x8*)(q_bf + (qbase + ctq * 16 + hh) * 128 + kc * 32 + qq * 8);

  const float* mrow0 = mask + (qbase + hh) * 2048;
  const float* mrow1 = mask + (qbase + 16 + hh) * 2048;
  const unsigned short* khl = k_hi + (long)b * 262144 + hh * 128 + qq * 8;
  const unsigned short* kll = k_lo + (long)b * 262144 + hh * 128 + qq * 8;
  const unsigned short* vl  = vT   + ((long)b * 128 + hh) * 2048 + qq * 8;

  f32x4 o_acc[8][2];
#pragma unroll
  for (int ht = 0; ht < 8; ++ht) { o_acc[ht][0] = zero4; o_acc[ht][1] = zero4; }
  float m_run[2] = {-3.0e38f, -3.0e38f};
  float l_run[2] = {0.f, 0.f};

  // prefetch mask tile 0 (C-frag layout: [kv = m*16+qq*4+r][q = ctq*16+hh])
  f32x4 mk[2][4];
#pragma unroll
  for (int m = 0; m < 4; ++m) {
    mk[0][m] = *(const f32x4*)(mrow0 + m * 16 + qq * 4);
    mk[1][m] = *(const f32x4*)(mrow1 + m * 16 + qq * 4);
  }

  const int src0 = (((qq << 1)) & 3) * 16 + hh;
  const int src1 = (((qq << 1) + 1) & 3) * 16 + hh;
  const bool hiq = qq >= 2;

  for (int t = 0; t < 32; ++t) {
    const int koff = t * 8192;   // t*64 rows * 128

    // S^T = K·Q^T (2-pass hi/lo K)
    f32x4 s[2][4];
#pragma unroll
    for (int m = 0; m < 4; ++m) { s[0][m] = zero4; s[1][m] = zero4; }
#pragma unroll
    for (int m = 0; m < 4; ++m) {
      bf16x8 khf[4], klf[4];
#pragma unroll
      for (int kc = 0; kc < 4; ++kc) {
        khf[kc] = *(const bf16x8*)(khl + koff + m * 2048 + kc * 32);
        klf[kc] = *(const bf16x8*)(kll + koff + m * 2048 + kc * 32);
      }
#pragma unroll
      for (int kc = 0; kc < 4; ++kc)
#pragma unroll
        for (int ctq = 0; ctq < 2; ++ctq) {
          s[ctq][m] = mfma16(khf[kc], qh[ctq][kc], s[ctq][m]);
          s[ctq][m] = mfma16(klf[kc], qh[ctq][kc], s[ctq][m]);
        }
    }

    // apply mask (consumes mk), then prefetch next tile's mask
#pragma unroll
    for (int ctq = 0; ctq < 2; ++ctq)
#pragma unroll
      for (int m = 0; m < 4; ++m) {
        f32x4 mv = mk[ctq][m];
        s[ctq][m] = mv * s[ctq][m] - NEGC * (1.0f - mv);
      }
    if (t + 1 < 32) {
      const int mo = (t + 1) * 64;
#pragma unroll
      for (int m = 0; m < 4; ++m) {
        mk[0][m] = *(const f32x4*)(mrow0 + mo + m * 16 + qq * 4);
        mk[1][m] = *(const f32x4*)(mrow1 + mo + m * 16 + qq * 4);
      }
    }

    // fp32 online softmax (per q col = hh; per-lane scalars)
    unsigned int pk[2][4][2];
#pragma unroll
    for (int ctq = 0; ctq < 2; ++ctq) {
      float mx = s[ctq][0][0];
#pragma unroll
      for (int m = 0; m < 4; ++m)
#pragma unroll
        for (int r = 0; r < 4; ++r) mx = fmaxf(mx, s[ctq][m][r]);
      mx = fmaxf(mx, __shfl_xor(mx, 16, 64));
      mx = fmaxf(mx, __shfl_xor(mx, 32, 64));
      float mnew = fmaxf(m_run[ctq], mx);
      float sc = exp2f((m_run[ctq] - mnew) * LOG2E);
      m_run[ctq] = mnew;
      float ps = 0.f;
#pragma unroll
      for (int m = 0; m < 4; ++m)
#pragma unroll
        for (int r = 0; r < 4; ++r) {
          float p = exp2f((s[ctq][m][r] - mnew) * LOG2E);
          s[ctq][m][r] = p;
          ps += p;
        }
      ps += __shfl_xor(ps, 16, 64);
      ps += __shfl_xor(ps, 32, 64);
      l_run[ctq] = l_run[ctq] * sc + ps;
#pragma unroll
      for (int ht = 0; ht < 8; ++ht) o_acc[ht][ctq] *= sc;
#pragma unroll
      for (int m = 0; m < 4; ++m) {
        pk[ctq][m][0] = pack2bf(s[ctq][m][0], s[ctq][m][1]);
        pk[ctq][m][1] = pack2bf(s[ctq][m][2], s[ctq][m][3]);
      }
    }

    // redistribute P (C layout) -> B-frag layout via shfl
    bf16x8 pb[2][2];
#pragma unroll
    for (int ctq = 0; ctq < 2; ++ctq)
#pragma unroll
      for (int c = 0; c < 2; ++c) {
        unsigned int a0 = (unsigned int)__shfl((int)pk[ctq][2 * c][0], src0, 64);
        unsigned int a1 = (unsigned int)__shfl((int)pk[ctq][2 * c][1], src0, 64);
        unsigned int a2 = (unsigned int)__shfl((int)pk[ctq][2 * c][0], src1, 64);
        unsigned int a3 = (unsigned int)__shfl((int)pk[ctq][2 * c][1], src1, 64);
        unsigned int b0 = (unsigned int)__shfl((int)pk[ctq][2 * c + 1][0], src0, 64);
        unsigned int b1 = (unsigned int)__shfl((int)pk[ctq][2 * c + 1][1], src0, 64);
        unsigned int b2 = (unsigned int)__shfl((int)pk[ctq][2 * c + 1][0], src1, 64);
        unsigned int b3 = (unsigned int)__shfl((int)pk[ctq][2 * c + 1][1], src1, 64);
        u32x4 w;
        w[0] = hiq ? b0 : a0;
        w[1] = hiq ? b1 : a1;
        w[2] = hiq ? b2 : a2;
        w[3] = hiq ? b3 : a3;
        pb[ctq][c] = __builtin_bit_cast(bf16x8, w);
      }

    // O^T += V^T · P
#pragma unroll
    for (int ht = 0; ht < 8; ++ht)
#pragma unroll
      for (int c = 0; c < 2; ++c) {
        bf16x8 vf = *(const bf16x8*)(vl + ht * 32768 + t * 64 + c * 32);
#pragma unroll
        for (int ctq = 0; ctq < 2; ++ctq)
          o_acc[ht][ctq] = mfma16(vf, pb[ctq][c], o_acc[ht][ctq]);
      }
  }

  // epilogue: normalize, store bf16. O^T frag: row h = ht*16+qq*4+r, col q = hh.
#pragma unroll
  for (int ctq = 0; ctq < 2; ++ctq) {
    float inv = 1.0f / l_run[ctq];
    const long row = qbase + ctq * 16 + hh;
#pragma unroll
    for (int ht = 0; ht < 8; ++ht) {
      f32x4 o = o_acc[ht][ctq];
      uint2 w;
      w.x = pack2bf(o[0] * inv, o[1] * inv);
      w.y = pack2bf(o[2] * inv, o[3] * inv);
      *(uint2*)(out_att + row * 128 + ht * 16 + qq * 4) = w;
    }
  }
}

// ---------------------------------------------------------------------------
// Kernel 3: out = relu(out_att @ Wout + bout) fused with the three heads.
// ---------------------------------------------------------------------------
__global__ __launch_bounds__(256) void wout_heads_kernel(
    const unsigned short* __restrict__ out_att, const unsigned short* __restrict__ WoutT,
    const float* __restrict__ bout,
    const float* __restrict__ Wval, const float* __restrict__ bval,
    const float* __restrict__ Wadv1, const float* __restrict__ badv1,
    const float* __restrict__ Wadv2, const float* __restrict__ badv2,
    float* __restrict__ value, float* __restrict__ adv1, float* __restrict__ adv2) {
  const int lane = threadIdx.x & 63, wid = threadIdx.x >> 6;
  const int qq = lane >> 4, hh = lane & 15;
  const long rowA = (long)blockIdx.x * 64 + wid * 16 + hh;
  const f32x4 zero4 = {0.f, 0.f, 0.f, 0.f};
  f32x4 acc[8];
#pragma unroll
  for (int t = 0; t < 8; ++t) acc[t] = zero4;
#pragma unroll
  for (int kc = 0; kc < 4; ++kc) {
    bf16x8 af = *(const bf16x8*)(out_att + rowA * 128 + kc * 32 + qq * 8);
#pragma unroll
    for (int t = 0; t < 8; ++t) {
      bf16x8 bf = *(const bf16x8*)(WoutT + (t * 16 + hh) * 128 + kc * 32 + qq * 8);
      acc[t] = mfma16(af, bf, acc[t]);
    }
  }
  float pv[4] = {0.f, 0.f, 0.f, 0.f};
  float pa1[4][8], pa2[4][8];
#pragma unroll
  for (int r = 0; r < 4; ++r)
#pragma unroll
    for (int j = 0; j < 8; ++j) { pa1[r][j] = 0.f; pa2[r][j] = 0.f; }
#pragma unroll
  for (int t = 0; t < 8; ++t) {
    const int col = t * 16 + hh;
    const float bo = bout[col];
    const float wv = Wval[col];
    const f32x4 w1a = *(const f32x4*)(Wadv1 + col * 8);
    const f32x4 w1b = *(const f32x4*)(Wadv1 + col * 8 + 4);
    const f32x4 w2a = *(const f32x4*)(Wadv2 + col * 8);
    const f32x4 w2b = *(const f32x4*)(Wadv2 + col * 8 + 4);
#pragma unroll
    for (int r = 0; r < 4; ++r) {
      float h = fmaxf(acc[t][r] + bo, 0.f);
      pv[r] += h * wv;
#pragma unroll
      for (int j = 0; j < 4; ++j) {
        pa1[r][j]     += h * w1a[j];
        pa1[r][4 + j] += h * w1b[j];
        pa2[r][j]     += h * w2a[j];
        pa2[r][4 + j] += h * w2b[j];
      }
    }
  }
#pragma unroll
  for (int r = 0; r < 4; ++r) {
#pragma unroll
    for (int s = 1; s < 16; s <<= 1) {
      pv[r] += __shfl_xor(pv[r], s, 64);
#pragma unroll
      for (int j = 0; j < 8; ++j) {
        pa1[r][j] += __shfl_xor(pa1[r][j], s, 64);
        pa2[r][j] += __shfl_xor(pa2[r][j], s, 64);
      }
    }
  }
  if (hh == 0) {
    const float bv0 = bval[0];
#pragma unroll
    for (int r = 0; r < 4; ++r) {
      const long row = (long)blockIdx.x * 64 + wid * 16 + qq * 4 + r;
      value[row] = pv[r] + bv0;
#pragma unroll
      for (int j = 0; j < 8; ++j) {
        adv1[row * 8 + j] = pa1[r][j] + badv1[j];
        adv2[row * 8 + j] = pa2[r][j] + badv2[j];
      }
    }
  }
}

// ---------------------------------------------------------------------------
// Kernel 4: per-batch column sums of adv1/adv2 over N (deterministic tree).
// ---------------------------------------------------------------------------
__global__ __launch_bounds__(256) void sums_kernel(const float* __restrict__ adv1,
                                                   const float* __restrict__ adv2,
                                                   float* __restrict__ sums) {
  const int b = blockIdx.x, tid = threadIdx.x;
  __shared__ float red[4][16];
  float p[16];
#pragma unroll
  for (int j = 0; j < 16; ++j) p[j] = 0.f;
  for (int n = tid; n < 2048; n += 256) {
    const long row = (long)b * 2048 + n;
    const f32x4 a1a = *(const f32x4*)(adv1 + row * 8);
    const f32x4 a1b = *(const f32x4*)(adv1 + row * 8 + 4);
    const f32x4 a2a = *(const f32x4*)(adv2 + row * 8);
    const f32x4 a2b = *(const f32x4*)(adv2 + row * 8 + 4);
#pragma unroll
    for (int j = 0; j < 4; ++j) {
      p[j] += a1a[j]; p[4 + j] += a1b[j];
      p[8 + j] += a2a[j]; p[12 + j] += a2b[j];
    }
  }
#pragma unroll
  for (int s = 1; s < 64; s <<= 1)
#pragma unroll
    for (int j = 0; j < 16; ++j) p[j] += __shfl_xor(p[j], s, 64);
  const int wid = tid >> 6;
  if ((tid & 63) == 0)
#pragma unroll
    for (int j = 0; j < 16; ++j) red[wid][j] = p[j];
  __syncthreads();
  if (tid < 16)
    sums[b * 16 + tid] = red[0][tid] + red[1][tid] + red[2][tid] + red[3][tid];
}

// ---------------------------------------------------------------------------
// Kernel 5: q1/q2 = value + adv - mean(adv). Output: [q1 | q2] fp32 flat.
// ---------------------------------------------------------------------------
__global__ void combine_kernel(const float* __restrict__ value, const float* __restrict__ adv1,
                               const float* __restrict__ adv2, const float* __restrict__ sums,
                               float* __restrict__ out) {
  const int idx = blockIdx.x * 256 + threadIdx.x;   // 0 .. 1048575
  const int half = 524288;
  const int which = (idx >= half) ? 1 : 0;
  const int rem = idx - which * half;
  const int b = rem >> 14;
  const int r2 = rem & 16383;
  const int n = r2 >> 3, j = r2 & 7;
  const long row = (long)b * 2048 + n;
  const float* adv = which ? adv2 : adv1;
  const float mean = sums[b * 16 + which * 8 + j] * (1.0f / 2048.0f);
  out[idx] = value[row] + adv[row * 8 + j] - mean;
}

// ---------------------------------------------------------------------------
extern "C" void kernel_launch(void* const* d_in, const int* in_sizes, int n_in,
                              void* d_out, int out_size, void* d_ws, size_t ws_size,
                              hipStream_t stream) {
  const float* x     = (const float*)d_in[0];
  const float* mask  = (const float*)d_in[1];
  const float* Wv    = (const float*)d_in[2];
  const float* bv    = (const float*)d_in[3];
  const float* Wk    = (const float*)d_in[4];
  const float* bk    = (const float*)d_in[5];
  const float* Wq    = (const float*)d_in[6];
  const float* bq    = (const float*)d_in[7];
  const float* Wout  = (const float*)d_in[8];
  const float* bout  = (const float*)d_in[9];
  const float* Wval  = (const float*)d_in[10];
  const float* bval  = (const float*)d_in[11];
  const float* Wadv1 = (const float*)d_in[12];
  const float* badv1 = (const float*)d_in[13];
  const float* Wadv2 = (const float*)d_in[14];
  const float* badv2 = (const float*)d_in[15];
  float* out = (float*)d_out;
  char* ws = (char*)d_ws;

  // workspace layout (bytes)
  unsigned short* q_bf   = (unsigned short*)(ws + 0);
  unsigned short* k_hi   = (unsigned short*)(ws + 16777216);
  unsigned short* k_lo   = (unsigned short*)(ws + 33554432);
  unsigned short* vT     = (unsigned short*)(ws + 50331648);
  unsigned short* out_at = (unsigned short*)(ws + 67108864);
  float* value = (float*)(ws + 83886080);
  float* adv1  = (float*)(ws + 84148224);
  float* adv2  = (float*)(ws + 86245376);
  float* sums  = (float*)(ws + 88342528);
  unsigned short* WT_hi = (unsigned short*)(ws + 88344576);
  unsigned short* WT_lo = (unsigned short*)(ws + 88541184);
  unsigned short* WoutT = (unsigned short*)(ws + 88737792);

  prep_kernel<<<448, 256, 0, stream>>>(Wv, Wk, Wq, Wout, WT_hi, WT_lo, WoutT);
  proj_kernel<<<1024, 256, 0, stream>>>(x, WT_hi, WT_lo, bq, bk, bv,
                                        q_bf, k_hi, k_lo, vT);
  attn_kernel<<<512, 256, 0, stream>>>(q_bf, k_hi, k_lo, vT, mask, out_at);
  wout_heads_kernel<<<1024, 256, 0, stream>>>(out_at, WoutT, bout, Wval, bval,
                                              Wadv1, badv1, Wadv2, badv2,
                                              value, adv1, adv2);
  sums_kernel<<<32, 256, 0, stream>>>(adv1, adv2, sums);
  combine_kernel<<<4096, 256, 0, stream>>>(value, adv1, adv2, sums, out);
}